// Round 1
// baseline (985.590 us; speedup 1.0000x reference)
//
#include <hip/hip_runtime.h>
#include <math.h>

#define EPSF 1e-8f

constexpr int Wd = 512;
constexpr int Hd = 512;
constexpr int Cd = 128;
constexpr int Bd = 2;
constexpr int HW = Hd * Wd;      // 262144 = 2^18
constexpr int NPLANE = Bd * Cd;  // 256

constexpr int STHREADS = 1024;
constexpr int NWAVES = STHREADS / 64;   // 16

constexpr int ATHREADS = 256;
constexpr int CHUNKS = 8;               // chunks per plane
constexpr int CROWS = Hd / CHUNKS;      // 64 rows per apply-block
constexpr int AITER = CROWS * Wd / 4 / ATHREADS;  // 32

typedef float f32x4 __attribute__((ext_vector_type(4)));

__device__ __forceinline__ void store_nt(float* p, float4 v) {
    __builtin_nontemporal_store(*(f32x4*)&v, (f32x4*)p);
}

// ---------------- Kernel 1: stats ----------------
// One block per (b,c) plane. Single coalesced pass over the plane; folds
// gamma/beta/mean/invstd into per-row, per-col, per-instance affine (a,b)
// pairs written to workspace (~2.1 MB total).
__global__ __launch_bounds__(STHREADS, 1)
void ircn_stats(const float* __restrict__ x,
                const float* __restrict__ gRow, const float* __restrict__ bRow,
                const float* __restrict__ gCol, const float* __restrict__ bCol,
                const float* __restrict__ gIns, const float* __restrict__ bIns,
                float* __restrict__ wsRowA, float* __restrict__ wsRowB,
                float* __restrict__ wsColA, float* __restrict__ wsColB,
                float* __restrict__ wsIns)
{
    __shared__ float sPartS[NWAVES][Wd];   // 32 KB col partial sums
    __shared__ float sPartQ[NWAVES][Wd];   // 32 KB col partial sumsq
    __shared__ float sWaveS[NWAVES], sWaveQ[NWAVES];

    const int plane = blockIdx.x;            // 0..255
    const int tid   = threadIdx.x;
    const int wave  = tid >> 6;
    const int lane  = tid & 63;
    const int c     = plane & (Cd - 1);

    const float gr = gRow[c], br = bRow[c];
    const float gc = gCol[c], bc = bCol[c];
    const float gi = gIns[c], bi = bIns[c];

    const float* __restrict__ px = x + (size_t)plane * HW;

    // lane owns columns 4*lane..4*lane+3 and 256+4*lane..256+4*lane+3
    float colS[8] = {0,0,0,0,0,0,0,0};
    float colQ[8] = {0,0,0,0,0,0,0,0};

    for (int r = wave; r < Hd; r += NWAVES) {
        const float4 a = *(const float4*)(px + (size_t)r * Wd + 4 * lane);
        const float4 d = *(const float4*)(px + (size_t)r * Wd + 256 + 4 * lane);
        float ax = a.x * a.x, ay = a.y * a.y, az = a.z * a.z, aw = a.w * a.w;
        float dx = d.x * d.x, dy = d.y * d.y, dz = d.z * d.z, dw = d.w * d.w;
        colS[0] += a.x; colS[1] += a.y; colS[2] += a.z; colS[3] += a.w;
        colS[4] += d.x; colS[5] += d.y; colS[6] += d.z; colS[7] += d.w;
        colQ[0] += ax;  colQ[1] += ay;  colQ[2] += az;  colQ[3] += aw;
        colQ[4] += dx;  colQ[5] += dy;  colQ[6] += dz;  colQ[7] += dw;

        float rs = (a.x + a.y) + (a.z + a.w) + (d.x + d.y) + (d.z + d.w);
        float rq = (ax + ay) + (az + aw) + (dx + dy) + (dz + dw);
        #pragma unroll
        for (int off = 32; off > 0; off >>= 1) {
            rs += __shfl_down(rs, off, 64);
            rq += __shfl_down(rq, off, 64);
        }
        if (lane == 0) {
            float m = rs * (1.0f / Wd);
            float v = fmaxf(rq * (1.0f / Wd) - m * m, 0.0f);
            float inv = 1.0f / (sqrtf(v + EPSF) + EPSF);
            float aa = gr * inv;
            wsRowA[plane * Hd + r] = aa;
            wsRowB[plane * Hd + r] = br - aa * m;
        }
    }

    // dump column partials to LDS (once per block)
    #pragma unroll
    for (int k = 0; k < 4; k++) {
        sPartS[wave][4 * lane + k]       = colS[k];
        sPartQ[wave][4 * lane + k]       = colQ[k];
        sPartS[wave][256 + 4 * lane + k] = colS[4 + k];
        sPartQ[wave][256 + 4 * lane + k] = colQ[4 + k];
    }
    __syncthreads();

    float insS = 0.0f, insQ = 0.0f;
    if (tid < Wd) {
        float s = 0.0f, q = 0.0f;
        #pragma unroll
        for (int wv = 0; wv < NWAVES; wv++) { s += sPartS[wv][tid]; q += sPartQ[wv][tid]; }
        float m = s * (1.0f / Hd);
        float v = fmaxf(q * (1.0f / Hd) - m * m, 0.0f);
        float inv = 1.0f / (sqrtf(v + EPSF) + EPSF);
        float aa = gc * inv;
        wsColA[plane * Wd + tid] = aa;
        wsColB[plane * Wd + tid] = bc - aa * m;
        insS = s; insQ = q;
    }
    // block-reduce instance sums (tid >= 512 contribute 0)
    #pragma unroll
    for (int off = 32; off > 0; off >>= 1) {
        insS += __shfl_down(insS, off, 64);
        insQ += __shfl_down(insQ, off, 64);
    }
    if (lane == 0) { sWaveS[wave] = insS; sWaveQ[wave] = insQ; }
    __syncthreads();
    if (tid == 0) {
        float S = 0.0f, Q = 0.0f;
        #pragma unroll
        for (int wv = 0; wv < NWAVES; wv++) { S += sWaveS[wv]; Q += sWaveQ[wv]; }
        float m = S * (1.0f / HW);
        float v = fmaxf(Q * (1.0f / HW) - m * m, 0.0f);
        float inv = 1.0f / (sqrtf(v + EPSF) + EPSF);
        float aa = gi * inv;
        wsIns[2 * plane]     = aa;
        wsIns[2 * plane + 1] = bi - aa * m;
    }
}

// ---------------- Kernel 2: apply (pure streaming) ----------------
// 8 blocks per plane, 64 rows each, 256 threads. Column coefficients are
// loop-invariant per thread (w4 = tid & 127 since 256 % 128 == 0) -> held
// in 8 registers. Row coefficients: 512 B LDS broadcast. No heavy LDS,
// no per-iteration cross-lane traffic -> max streaming concurrency.
__global__ __launch_bounds__(ATHREADS, 4)
void ircn_apply(const float* __restrict__ x,
                const float* __restrict__ wsRowA, const float* __restrict__ wsRowB,
                const float* __restrict__ wsColA, const float* __restrict__ wsColB,
                const float* __restrict__ wsIns,
                float* __restrict__ out)
{
    __shared__ float sRowA[CROWS], sRowB[CROWS];

    const int tid   = threadIdx.x;
    const int blk   = blockIdx.x;
    const int plane = blk >> 3;              // 0..255
    const int chunk = blk & (CHUNKS - 1);    // 0..7
    const int c     = plane & (Cd - 1);
    const int r0    = chunk * CROWS;

    if (tid < CROWS) {
        sRowA[tid] = wsRowA[plane * Hd + r0 + tid];
        sRowB[tid] = wsRowB[plane * Hd + r0 + tid];
    }
    const int w4    = tid & 127;             // fixed column-group per thread
    const int hbase = tid >> 7;              // 0 or 1 (uniform per wave)
    const float4 aC = *(const float4*)(wsColA + plane * Wd + 4 * w4);
    const float4 bC = *(const float4*)(wsColB + plane * Wd + 4 * w4);
    const float  aI = wsIns[2 * plane];
    const float  bI = wsIns[2 * plane + 1];
    __syncthreads();

    const size_t chunkOff = (size_t)r0 * Wd;
    const float* __restrict__ px = x + (size_t)plane * HW + chunkOff;
    const size_t baseIns = ((size_t)((plane >> 7) * 3 * Cd + c)) << 18;
    float* __restrict__ outIns = out + baseIns + chunkOff;
    float* __restrict__ outRow = outIns + ((size_t)Cd << 18);
    float* __restrict__ outCol = outIns + ((size_t)(2 * Cd) << 18);

    #pragma unroll 2
    for (int it = 0; it < AITER; ++it) {
        const int h = 2 * it + hbase;                 // local row 0..63
        const size_t off = (size_t)h * Wd + 4 * w4;
        const float4 xv = *(const float4*)(px + off);
        const float aR = sRowA[h], bR = sRowB[h];

        float4 oI, oR, oC;
        oI.x = fmaf(aI, xv.x, bI);     oI.y = fmaf(aI, xv.y, bI);
        oI.z = fmaf(aI, xv.z, bI);     oI.w = fmaf(aI, xv.w, bI);
        oR.x = fmaf(aR, xv.x, bR);     oR.y = fmaf(aR, xv.y, bR);
        oR.z = fmaf(aR, xv.z, bR);     oR.w = fmaf(aR, xv.w, bR);
        oC.x = fmaf(aC.x, xv.x, bC.x); oC.y = fmaf(aC.y, xv.y, bC.y);
        oC.z = fmaf(aC.z, xv.z, bC.z); oC.w = fmaf(aC.w, xv.w, bC.w);

        store_nt(outIns + off, oI);
        store_nt(outRow + off, oR);
        store_nt(outCol + off, oC);
    }
}

extern "C" void kernel_launch(void* const* d_in, const int* in_sizes, int n_in,
                              void* d_out, int out_size, void* d_ws, size_t ws_size,
                              hipStream_t stream) {
    const float* x    = (const float*)d_in[0];
    const float* gRow = (const float*)d_in[1];
    const float* bRow = (const float*)d_in[2];
    const float* gCol = (const float*)d_in[3];
    const float* bCol = (const float*)d_in[4];
    const float* gIns = (const float*)d_in[5];
    const float* bIns = (const float*)d_in[6];
    float* out = (float*)d_out;

    // workspace layout (floats): rowA[256*512] rowB[256*512] colA[256*512]
    // colB[256*512] ins[256*2]  -> ~2.1 MB
    float* ws     = (float*)d_ws;
    float* wsRowA = ws;
    float* wsRowB = wsRowA + (size_t)NPLANE * Hd;
    float* wsColA = wsRowB + (size_t)NPLANE * Hd;
    float* wsColB = wsColA + (size_t)NPLANE * Wd;
    float* wsIns  = wsColB + (size_t)NPLANE * Wd;

    ircn_stats<<<NPLANE, STHREADS, 0, stream>>>(x, gRow, bRow, gCol, bCol,
                                                gIns, bIns,
                                                wsRowA, wsRowB, wsColA, wsColB, wsIns);
    ircn_apply<<<NPLANE * CHUNKS, ATHREADS, 0, stream>>>(x, wsRowA, wsRowB,
                                                         wsColA, wsColB, wsIns, out);
}